// Round 1
// baseline (538.801 us; speedup 1.0000x reference)
//
#include <hip/hip_runtime.h>
#include <math.h>

#define N_NODES_C 50000
#define N_EDGES_C 200000
#define FDIM 128
#define NRBF 20
#define CUT 5.0f

// ---------------------------------------------------------------------------
// Fused node MLP: phi = silu(s@W1 + b1) @ W2 + b2        (per 32-node tile)
// ---------------------------------------------------------------------------
__global__ __launch_bounds__(256) void mlp_kernel(
    const float* __restrict__ s, const float* __restrict__ W1,
    const float* __restrict__ b1, const float* __restrict__ W2,
    const float* __restrict__ b2, float* __restrict__ phi)
{
    __shared__ float sT[128 * 36];   // s tile transposed [k][node], pad to 36
    __shared__ float hT[128 * 36];   // h tile transposed [k][node]
    __shared__ float wl[16 * 384];   // weight chunk: [32][128] (A) or [16][384] (B)

    const int tid = threadIdx.x;
    const int nb  = blockIdx.x * 32;

    // ---- load s tile (32 nodes x 128) transposed into sT ----
#pragma unroll
    for (int j = 0; j < 4; ++j) {
        int fi   = tid + j * 256;        // 0..1023 float4 index
        int node = fi >> 5;              // 32 float4 per row
        int kq   = fi & 31;
        int gn   = nb + node; if (gn >= N_NODES_C) gn = N_NODES_C - 1;
        float4 val = *(const float4*)(s + (size_t)gn * FDIM + kq * 4);
        sT[(kq * 4 + 0) * 36 + node] = val.x;
        sT[(kq * 4 + 1) * 36 + node] = val.y;
        sT[(kq * 4 + 2) * 36 + node] = val.z;
        sT[(kq * 4 + 3) * 36 + node] = val.w;
    }

    const int tn = tid >> 5;   // 0..7
    const int tc = tid & 31;   // 0..31
    const int n0 = tn * 4;

    // ---------------- stage 1: h = silu(s@W1 + b1) ----------------
    float acc[4][4];
#pragma unroll
    for (int i = 0; i < 4; ++i)
#pragma unroll
        for (int j = 0; j < 4; ++j) acc[i][j] = 0.f;

    for (int kt = 0; kt < 4; ++kt) {
        __syncthreads();
#pragma unroll
        for (int j = 0; j < 4; ++j) {
            int fi = tid + j * 256;
            int row = fi >> 5;
            int cq  = fi & 31;
            *(float4*)(wl + row * 128 + cq * 4) =
                *(const float4*)(W1 + (size_t)(kt * 32 + row) * FDIM + cq * 4);
        }
        __syncthreads();
#pragma unroll
        for (int k = 0; k < 32; ++k) {
            float4 a = *(const float4*)(sT + (kt * 32 + k) * 36 + n0);
            float4 b = *(const float4*)(wl + k * 128 + tc * 4);
            float av[4] = {a.x, a.y, a.z, a.w};
            float bv[4] = {b.x, b.y, b.z, b.w};
#pragma unroll
            for (int i = 0; i < 4; ++i)
#pragma unroll
                for (int jj = 0; jj < 4; ++jj)
                    acc[i][jj] += av[i] * bv[jj];
        }
    }

    // silu + transpose into hT
    {
        float4 bb = *(const float4*)(b1 + tc * 4);
        float bbv[4] = {bb.x, bb.y, bb.z, bb.w};
#pragma unroll
        for (int i = 0; i < 4; ++i)
#pragma unroll
            for (int jj = 0; jj < 4; ++jj) {
                float h = acc[i][jj] + bbv[jj];
                h = h / (1.f + __expf(-h));
                hT[(tc * 4 + jj) * 36 + n0 + i] = h;
            }
    }

    // ---------------- stage 2: phi = h@W2 + b2 ----------------
    float acc2[4][12];
#pragma unroll
    for (int i = 0; i < 4; ++i)
#pragma unroll
        for (int j = 0; j < 12; ++j) acc2[i][j] = 0.f;

    for (int kt = 0; kt < 8; ++kt) {
        __syncthreads();   // also guards hT writes (kt==0) and wl reuse
#pragma unroll
        for (int j = 0; j < 6; ++j) {
            int fi = tid + j * 256;     // 0..1535 float4 index
            int row = fi / 96;          // 96 float4 per row of 384
            int cq  = fi % 96;
            *(float4*)(wl + row * 384 + cq * 4) =
                *(const float4*)(W2 + (size_t)(kt * 16 + row) * 384 + cq * 4);
        }
        __syncthreads();
#pragma unroll
        for (int k = 0; k < 16; ++k) {
            float4 a = *(const float4*)(hT + (kt * 16 + k) * 36 + n0);
            float av[4] = {a.x, a.y, a.z, a.w};
#pragma unroll
            for (int p = 0; p < 3; ++p) {
                float4 b = *(const float4*)(wl + k * 384 + p * 128 + tc * 4);
                float bv[4] = {b.x, b.y, b.z, b.w};
#pragma unroll
                for (int i = 0; i < 4; ++i)
#pragma unroll
                    for (int q = 0; q < 4; ++q)
                        acc2[i][p * 4 + q] += av[i] * bv[q];
            }
        }
    }

    // bias + store
#pragma unroll
    for (int p = 0; p < 3; ++p) {
        float4 bb = *(const float4*)(b2 + p * 128 + tc * 4);
        float bbv[4] = {bb.x, bb.y, bb.z, bb.w};
#pragma unroll
        for (int i = 0; i < 4; ++i) {
            int gn = nb + n0 + i;
            if (gn < N_NODES_C) {
                float4 o;
                o.x = acc2[i][p * 4 + 0] + bbv[0];
                o.y = acc2[i][p * 4 + 1] + bbv[1];
                o.z = acc2[i][p * 4 + 2] + bbv[2];
                o.w = acc2[i][p * 4 + 3] + bbv[3];
                *(float4*)(phi + (size_t)gn * 384 + p * 128 + tc * 4) = o;
            }
        }
    }
}

// ---------------------------------------------------------------------------
// Edge kernel: RBF -> w -> split -> scatter-add (atomics)
// ---------------------------------------------------------------------------
__global__ __launch_bounds__(256) void edge_kernel(
    const float* __restrict__ v, const float* __restrict__ rel_pos,
    const float* __restrict__ Wr, const float* __restrict__ br,
    const int* __restrict__ src, const int* __restrict__ dst,
    const float* __restrict__ phi, float* __restrict__ out_v,
    float* __restrict__ out_s)
{
    __shared__ float wr_l[NRBF * 384];
    __shared__ float br_l[384];

    for (int i = threadIdx.x; i < NRBF * 384; i += 256) wr_l[i] = Wr[i];
    for (int i = threadIdx.x; i < 384; i += 256) br_l[i] = br[i];
    __syncthreads();

    const int grp = threadIdx.x >> 7;    // 2 edges per block-iteration
    const int f   = threadIdx.x & 127;
    const float k1 = 3.14159265358979f / CUT;

    for (int e = blockIdx.x * 2 + grp; e < N_EDGES_C; e += gridDim.x * 2) {
        float x = rel_pos[3 * e + 0];
        float y = rel_pos[3 * e + 1];
        float z = rel_pos[3 * e + 2];
        float d = sqrtf(x * x + y * y + z * z);
        float invd = 1.0f / d;
        float s1, c1;
        sincosf(k1 * d, &s1, &c1);
        float fcut = (d < CUT) ? 0.5f * (c1 + 1.0f) : 0.0f;

        // w_proj via sin(n*theta) recurrence
        float a0 = 0.f, a1 = 0.f, a2 = 0.f;
        float sk = s1, ck = c1;
#pragma unroll
        for (int k = 0; k < NRBF; ++k) {
            float rb = sk * invd;
            a0 += rb * wr_l[k * 384 + f];
            a1 += rb * wr_l[k * 384 + 128 + f];
            a2 += rb * wr_l[k * 384 + 256 + f];
            float sn = sk * c1 + ck * s1;
            ck = ck * c1 - sk * s1;
            sk = sn;
        }
        float w0 = (a0 + br_l[f]) * fcut;
        float w1 = (a1 + br_l[128 + f]) * fcut;
        float w2 = (a2 + br_l[256 + f]) * fcut;

        int si = src[e], di = dst[e];
        const float* ph = phi + (size_t)si * 384;
        float sv = w0 * ph[f];
        float ss = w1 * ph[128 + f];
        float sr = w2 * ph[256 + f];

        atomicAdd(out_s + (size_t)di * 128 + f, ss);

        float dx = x * invd, dy = y * invd, dz = z * invd;
        const float* vr = v + (size_t)si * 384;
        atomicAdd(out_v + (size_t)di * 384 +       f, vr[f]       * sv + dx * sr);
        atomicAdd(out_v + (size_t)di * 384 + 128 + f, vr[128 + f] * sv + dy * sr);
        atomicAdd(out_v + (size_t)di * 384 + 256 + f, vr[256 + f] * sv + dz * sr);
    }
}

// ---------------------------------------------------------------------------
extern "C" void kernel_launch(void* const* d_in, const int* in_sizes, int n_in,
                              void* d_out, int out_size, void* d_ws, size_t ws_size,
                              hipStream_t stream)
{
    const float* s  = (const float*)d_in[0];
    const float* v  = (const float*)d_in[1];
    const float* rp = (const float*)d_in[2];
    const float* W1 = (const float*)d_in[3];
    const float* b1 = (const float*)d_in[4];
    const float* W2 = (const float*)d_in[5];
    const float* b2 = (const float*)d_in[6];
    const float* Wr = (const float*)d_in[7];
    const float* br = (const float*)d_in[8];
    const int* src  = (const int*)d_in[9];
    const int* dst  = (const int*)d_in[10];

    float* out   = (float*)d_out;
    float* out_v = out;                                    // 50000*3*128
    float* out_s = out + (size_t)N_NODES_C * 3 * FDIM;     // 50000*128
    float* phi   = (float*)d_ws;                           // 50000*384 floats

    // atomically-accumulated outputs must start at zero every call
    hipMemsetAsync(d_out, 0, (size_t)out_size * sizeof(float), stream);

    mlp_kernel<<<(N_NODES_C + 31) / 32, 256, 0, stream>>>(s, W1, b1, W2, b2, phi);
    edge_kernel<<<4096, 256, 0, stream>>>(v, rp, Wr, br, src, dst, phi, out_v, out_s);
}

// Round 2
// 472.579 us; speedup vs baseline: 1.1401x; 1.1401x over previous
//
#include <hip/hip_runtime.h>
#include <math.h>

#define N_NODES_C 50000
#define N_EDGES_C 200000
#define FDIM 128
#define NRBF 20
#define CUT 5.0f

// ---------------------------------------------------------------------------
// Fused node MLP: phi = silu(s@W1 + b1) @ W2 + b2        (per 32-node tile)
// ---------------------------------------------------------------------------
__global__ __launch_bounds__(256) void mlp_kernel(
    const float* __restrict__ s, const float* __restrict__ W1,
    const float* __restrict__ b1, const float* __restrict__ W2,
    const float* __restrict__ b2, float* __restrict__ phi)
{
    __shared__ float sT[128 * 36];   // s tile transposed [k][node], pad to 36
    __shared__ float hT[128 * 36];   // h tile transposed [k][node]
    __shared__ float wl[16 * 384];   // weight chunk: [32][128] (A) or [16][384] (B)

    const int tid = threadIdx.x;
    const int nb  = blockIdx.x * 32;

    // ---- load s tile (32 nodes x 128) transposed into sT ----
#pragma unroll
    for (int j = 0; j < 4; ++j) {
        int fi   = tid + j * 256;        // 0..1023 float4 index
        int node = fi >> 5;              // 32 float4 per row
        int kq   = fi & 31;
        int gn   = nb + node; if (gn >= N_NODES_C) gn = N_NODES_C - 1;
        float4 val = *(const float4*)(s + (size_t)gn * FDIM + kq * 4);
        sT[(kq * 4 + 0) * 36 + node] = val.x;
        sT[(kq * 4 + 1) * 36 + node] = val.y;
        sT[(kq * 4 + 2) * 36 + node] = val.z;
        sT[(kq * 4 + 3) * 36 + node] = val.w;
    }

    const int tn = tid >> 5;   // 0..7
    const int tc = tid & 31;   // 0..31
    const int n0 = tn * 4;

    // ---------------- stage 1: h = silu(s@W1 + b1) ----------------
    float acc[4][4];
#pragma unroll
    for (int i = 0; i < 4; ++i)
#pragma unroll
        for (int j = 0; j < 4; ++j) acc[i][j] = 0.f;

    for (int kt = 0; kt < 4; ++kt) {
        __syncthreads();
#pragma unroll
        for (int j = 0; j < 4; ++j) {
            int fi = tid + j * 256;
            int row = fi >> 5;
            int cq  = fi & 31;
            *(float4*)(wl + row * 128 + cq * 4) =
                *(const float4*)(W1 + (size_t)(kt * 32 + row) * FDIM + cq * 4);
        }
        __syncthreads();
#pragma unroll
        for (int k = 0; k < 32; ++k) {
            float4 a = *(const float4*)(sT + (kt * 32 + k) * 36 + n0);
            float4 b = *(const float4*)(wl + k * 128 + tc * 4);
            float av[4] = {a.x, a.y, a.z, a.w};
            float bv[4] = {b.x, b.y, b.z, b.w};
#pragma unroll
            for (int i = 0; i < 4; ++i)
#pragma unroll
                for (int jj = 0; jj < 4; ++jj)
                    acc[i][jj] += av[i] * bv[jj];
        }
    }

    // silu + transpose into hT
    {
        float4 bb = *(const float4*)(b1 + tc * 4);
        float bbv[4] = {bb.x, bb.y, bb.z, bb.w};
#pragma unroll
        for (int i = 0; i < 4; ++i)
#pragma unroll
            for (int jj = 0; jj < 4; ++jj) {
                float h = acc[i][jj] + bbv[jj];
                h = h / (1.f + __expf(-h));
                hT[(tc * 4 + jj) * 36 + n0 + i] = h;
            }
    }

    // ---------------- stage 2: phi = h@W2 + b2 ----------------
    float acc2[4][12];
#pragma unroll
    for (int i = 0; i < 4; ++i)
#pragma unroll
        for (int j = 0; j < 12; ++j) acc2[i][j] = 0.f;

    for (int kt = 0; kt < 8; ++kt) {
        __syncthreads();   // also guards hT writes (kt==0) and wl reuse
#pragma unroll
        for (int j = 0; j < 6; ++j) {
            int fi = tid + j * 256;     // 0..1535 float4 index
            int row = fi / 96;          // 96 float4 per row of 384
            int cq  = fi % 96;
            *(float4*)(wl + row * 384 + cq * 4) =
                *(const float4*)(W2 + (size_t)(kt * 16 + row) * 384 + cq * 4);
        }
        __syncthreads();
#pragma unroll
        for (int k = 0; k < 16; ++k) {
            float4 a = *(const float4*)(hT + (kt * 16 + k) * 36 + n0);
            float av[4] = {a.x, a.y, a.z, a.w};
#pragma unroll
            for (int p = 0; p < 3; ++p) {
                float4 b = *(const float4*)(wl + k * 384 + p * 128 + tc * 4);
                float bv[4] = {b.x, b.y, b.z, b.w};
#pragma unroll
                for (int i = 0; i < 4; ++i)
#pragma unroll
                    for (int q = 0; q < 4; ++q)
                        acc2[i][p * 4 + q] += av[i] * bv[q];
            }
        }
    }

    // bias + store
#pragma unroll
    for (int p = 0; p < 3; ++p) {
        float4 bb = *(const float4*)(b2 + p * 128 + tc * 4);
        float bbv[4] = {bb.x, bb.y, bb.z, bb.w};
#pragma unroll
        for (int i = 0; i < 4; ++i) {
            int gn = nb + n0 + i;
            if (gn < N_NODES_C) {
                float4 o;
                o.x = acc2[i][p * 4 + 0] + bbv[0];
                o.y = acc2[i][p * 4 + 1] + bbv[1];
                o.z = acc2[i][p * 4 + 2] + bbv[2];
                o.w = acc2[i][p * 4 + 3] + bbv[3];
                *(float4*)(phi + (size_t)gn * 384 + p * 128 + tc * 4) = o;
            }
        }
    }
}

// ---------------------------------------------------------------------------
// Build per-dst linked lists: head[n] -> chain of edges via next[e]
// ---------------------------------------------------------------------------
__global__ __launch_bounds__(256) void build_lists_kernel(
    const int* __restrict__ dst, int* __restrict__ head, int* __restrict__ next)
{
    int e = blockIdx.x * 256 + threadIdx.x;
    if (e < N_EDGES_C) {
        next[e] = atomicExch(head + dst[e], e);
    }
}

// ---------------------------------------------------------------------------
// Gather kernel: per dst node, walk edge list, accumulate in registers,
// single coalesced store. No output atomics, no output pre-zeroing needed.
// ---------------------------------------------------------------------------
__global__ __launch_bounds__(256) void gather_kernel(
    const float* __restrict__ v, const float* __restrict__ rel_pos,
    const float* __restrict__ Wr, const float* __restrict__ br,
    const int* __restrict__ src, const int* __restrict__ head,
    const int* __restrict__ next, const float* __restrict__ phi,
    float* __restrict__ out_v, float* __restrict__ out_s)
{
    __shared__ float wr_l[NRBF * 384];
    __shared__ float br_l[384];

    for (int i = threadIdx.x; i < NRBF * 384; i += 256) wr_l[i] = Wr[i];
    for (int i = threadIdx.x; i < 384; i += 256) br_l[i] = br[i];
    __syncthreads();

    const int grp = threadIdx.x >> 7;    // 2 dst nodes per block
    const int f   = threadIdx.x & 127;
    const int n   = blockIdx.x * 2 + grp;    // grid = 25000 exact, n < 50000
    const float k1 = 3.14159265358979f / CUT;

    float acc_s = 0.f, acc_v0 = 0.f, acc_v1 = 0.f, acc_v2 = 0.f;

    for (int e = head[n]; e >= 0; ) {
        int en = next[e];                // prefetch chain pointer early

        float x = rel_pos[3 * e + 0];
        float y = rel_pos[3 * e + 1];
        float z = rel_pos[3 * e + 2];
        float d = sqrtf(x * x + y * y + z * z);

        if (d >= CUT) { e = en; continue; }   // fcut == 0 -> zero contribution

        float invd = 1.0f / d;
        float s1, c1;
        sincosf(k1 * d, &s1, &c1);
        float fcut = 0.5f * (c1 + 1.0f);

        // w_proj via sin(n*theta) recurrence
        float a0 = 0.f, a1 = 0.f, a2 = 0.f;
        float sk = s1, ck = c1;
#pragma unroll
        for (int k = 0; k < NRBF; ++k) {
            float rb = sk * invd;
            a0 += rb * wr_l[k * 384 + f];
            a1 += rb * wr_l[k * 384 + 128 + f];
            a2 += rb * wr_l[k * 384 + 256 + f];
            float sn = sk * c1 + ck * s1;
            ck = ck * c1 - sk * s1;
            sk = sn;
        }
        float w0 = (a0 + br_l[f]) * fcut;
        float w1 = (a1 + br_l[128 + f]) * fcut;
        float w2 = (a2 + br_l[256 + f]) * fcut;

        int si = src[e];
        const float* ph = phi + (size_t)si * 384;
        float sv = w0 * ph[f];
        float ss = w1 * ph[128 + f];
        float sr = w2 * ph[256 + f];

        float dx = x * invd, dy = y * invd, dz = z * invd;
        const float* vr = v + (size_t)si * 384;

        acc_s  += ss;
        acc_v0 += vr[f]       * sv + dx * sr;
        acc_v1 += vr[128 + f] * sv + dy * sr;
        acc_v2 += vr[256 + f] * sv + dz * sr;

        e = en;
    }

    out_s[(size_t)n * 128 + f] = acc_s;
    out_v[(size_t)n * 384 +       f] = acc_v0;
    out_v[(size_t)n * 384 + 128 + f] = acc_v1;
    out_v[(size_t)n * 384 + 256 + f] = acc_v2;
}

// ---------------------------------------------------------------------------
extern "C" void kernel_launch(void* const* d_in, const int* in_sizes, int n_in,
                              void* d_out, int out_size, void* d_ws, size_t ws_size,
                              hipStream_t stream)
{
    const float* s  = (const float*)d_in[0];
    const float* v  = (const float*)d_in[1];
    const float* rp = (const float*)d_in[2];
    const float* W1 = (const float*)d_in[3];
    const float* b1 = (const float*)d_in[4];
    const float* W2 = (const float*)d_in[5];
    const float* b2 = (const float*)d_in[6];
    const float* Wr = (const float*)d_in[7];
    const float* br = (const float*)d_in[8];
    const int* src  = (const int*)d_in[9];
    const int* dst  = (const int*)d_in[10];

    float* out   = (float*)d_out;
    float* out_v = out;                                    // 50000*3*128
    float* out_s = out + (size_t)N_NODES_C * 3 * FDIM;     // 50000*128

    // workspace layout
    float* phi  = (float*)d_ws;                            // 50000*384 floats
    int*   head = (int*)((char*)d_ws + (size_t)N_NODES_C * 384 * sizeof(float));
    int*   next = head + N_NODES_C;

    // head[] = -1 (0xFFFFFFFF)
    hipMemsetAsync(head, 0xFF, (size_t)N_NODES_C * sizeof(int), stream);

    build_lists_kernel<<<(N_EDGES_C + 255) / 256, 256, 0, stream>>>(dst, head, next);
    mlp_kernel<<<(N_NODES_C + 31) / 32, 256, 0, stream>>>(s, W1, b1, W2, b2, phi);
    gather_kernel<<<N_NODES_C / 2, 256, 0, stream>>>(v, rp, Wr, br, src, head, next,
                                                     phi, out_v, out_s);
}